// Round 1
// baseline (13588.039 us; speedup 1.0000x reference)
//
#include <hip/hip_runtime.h>
#include <hip/hip_bf16.h>
#include <math.h>

#define B_ 2
#define S_ 1024
#define D_ 1024
#define H_ 16
#define DK_ 64
#define L_ 4
#define FF_ 4096
#define V_ 32000
#define NT (B_*S_)   // 2048 tokens
#define QT 16        // q rows per attention block

// ---------------- embed: x = emb[ids] * sqrt(D) ----------------
__global__ __launch_bounds__(256) void k_embed(const int* __restrict__ ids,
    const float* __restrict__ emb, float* __restrict__ x) {
  int i = blockIdx.x*256 + threadIdx.x;
  if (i >= NT*D_) return;
  int tok = i >> 10;
  int d = i & 1023;
  x[i] = emb[(size_t)ids[tok]*D_ + d] * 32.0f;
}

// ---------------- rmsnorm: o = w * x / sqrt(mean(x^2)+1e-8) ----------------
__global__ __launch_bounds__(256) void k_rms(const float* __restrict__ x,
    const float* __restrict__ w, float* __restrict__ o) {
  int row = blockIdx.x;
  const float* xr = x + (size_t)row*D_;
  float s = 0.f;
  for (int d = threadIdx.x; d < D_; d += 256) { float v = xr[d]; s += v*v; }
  for (int off = 32; off; off >>= 1) s += __shfl_down(s, off);
  __shared__ float red[4];
  __shared__ float inv_s;
  int wid = threadIdx.x >> 6;
  if ((threadIdx.x & 63) == 0) red[wid] = s;
  __syncthreads();
  if (threadIdx.x == 0) {
    float t = red[0]+red[1]+red[2]+red[3];
    inv_s = 1.0f / sqrtf(t * (1.0f/D_) + 1e-8f);
  }
  __syncthreads();
  float inv = inv_s;
  float* orow = o + (size_t)row*D_;
  for (int d = threadIdx.x; d < D_; d += 256) orow[d] = w[d]*xr[d]*inv;
}

// ---------------- GEMM: C[M,N] = A[M,K] @ B  (+ optional residual) ----------
// BT=false: B is [K,N] row-major.  BT=true: B is [N,K] row-major (B^T GEMM).
// 128x128 tile, BK=16, 256 threads, 8x8 micro-tile per thread.
template<bool BT, bool RES>
__global__ __launch_bounds__(256) void k_gemm(const float* __restrict__ A,
    const float* __restrict__ Bm, const float* __restrict__ res,
    float* __restrict__ C, int M, int N, int K) {
  __shared__ float As[16][129];
  __shared__ float Bs[16][129];
  const int bm = blockIdx.y * 128;
  const int bn = blockIdx.x * 128;
  const int tid = threadIdx.x;
  const int tr = tid >> 4;
  const int tc = tid & 15;
  float acc[8][8];
  #pragma unroll
  for (int i=0;i<8;i++)
    #pragma unroll
    for (int j=0;j<8;j++) acc[i][j]=0.f;

  for (int k0 = 0; k0 < K; k0 += 16) {
    #pragma unroll
    for (int i = 0; i < 8; ++i) {            // A tile: 128x16
      int idx = tid + i*256;
      int r = idx >> 4, c = idx & 15;
      As[c][r] = A[(size_t)(bm+r)*K + k0 + c];
    }
    #pragma unroll
    for (int i = 0; i < 8; ++i) {            // B tile: 16x128
      int idx = tid + i*256;
      if constexpr (BT) {
        int n = idx >> 4, kk = idx & 15;
        Bs[kk][n] = Bm[(size_t)(bn+n)*K + k0 + kk];
      } else {
        int kk = idx >> 7, n = idx & 127;
        Bs[kk][n] = Bm[(size_t)(k0+kk)*N + bn + n];
      }
    }
    __syncthreads();
    #pragma unroll
    for (int kk = 0; kk < 16; ++kk) {
      float a[8], b[8];
      #pragma unroll
      for (int i=0;i<8;i++) a[i] = As[kk][tr*8+i];
      #pragma unroll
      for (int j=0;j<8;j++) b[j] = Bs[kk][tc*8+j];
      #pragma unroll
      for (int i=0;i<8;i++)
        #pragma unroll
        for (int j=0;j<8;j++) acc[i][j] += a[i]*b[j];
    }
    __syncthreads();
  }
  #pragma unroll
  for (int i=0;i<8;i++) {
    size_t rowoff = (size_t)(bm + tr*8 + i)*N + bn + tc*8;
    #pragma unroll
    for (int j=0;j<8;j++) {
      float v = acc[i][j];
      if constexpr (RES) v += res[rowoff + j];
      C[rowoff + j] = v;
    }
  }
}

// ---------------- RoPE factor (elementwise multiply on q,k) ----------------
// factor(s, dk) = cos(s*f) + sin(s*f), f = exp(-(dk%32) * log(10000)/32)
__global__ __launch_bounds__(256) void k_rope(float* __restrict__ qkv) {
  int i = blockIdx.x*256 + threadIdx.x;
  if (i >= NT*2048) return;
  int tok = i >> 11;
  int c = i & 2047;              // cols [0,1024)=q, [1024,2048)=k
  int dk = c & 63;
  int j = dk & 31;
  int s = tok & (S_-1);
  float freq = expf((float)j * -0.28782313662425574f);  // -log(10000)/32
  float ang = (float)s * freq;
  qkv[(size_t)tok*3072 + c] *= (cosf(ang) + sinf(ang));
}

// ---------------- attention: per (b,h,16-row q tile), scores in LDS --------
__global__ __launch_bounds__(256) void k_attn(const float* __restrict__ qkv,
    float* __restrict__ out) {
  const int qt = blockIdx.x;
  const int h  = blockIdx.y;
  const int b  = blockIdx.z;
  const int tid = threadIdx.x;
  __shared__ float q_s[QT][DK_];
  __shared__ float sc[QT][S_];        // 64 KB
  __shared__ float red[QT][17];
  __shared__ float rowmax[QT], rowinv[QT];

  const int s0 = qt*QT;
  for (int i = tid; i < QT*DK_; i += 256) {
    int r = i >> 6, c = i & 63;
    q_s[r][c] = qkv[((size_t)(b*S_ + s0 + r))*3072 + h*DK_ + c];
  }
  __syncthreads();

  const int smax_tile = s0 + QT - 1;
  for (int t = tid; t < S_; t += 256) {
    if (t > smax_tile) {
      #pragma unroll
      for (int r=0;r<QT;r++) sc[r][t] = -1e9f;
      continue;
    }
    float acc[QT];
    #pragma unroll
    for (int r=0;r<QT;r++) acc[r]=0.f;
    const float* kp = qkv + ((size_t)(b*S_ + t))*3072 + 1024 + h*DK_;
    #pragma unroll
    for (int c=0;c<DK_;c+=4) {
      float4 kv = *(const float4*)(kp + c);
      #pragma unroll
      for (int r=0;r<QT;r++) {
        float4 qv = *(const float4*)(&q_s[r][c]);
        acc[r] += qv.x*kv.x + qv.y*kv.y + qv.z*kv.z + qv.w*kv.w;
      }
    }
    #pragma unroll
    for (int r=0;r<QT;r++) sc[r][t] = (t <= s0+r) ? acc[r]*0.125f : -1e9f;
  }
  __syncthreads();

  // row softmax over 1024 cols; 16 threads per row
  {
    int r = tid & 15, seg = tid >> 4;
    float mx = -1e30f;
    for (int t = seg*64; t < seg*64+64; ++t) mx = fmaxf(mx, sc[r][t]);
    red[r][seg] = mx;
    __syncthreads();
    if (tid < QT) {
      float m = -1e30f;
      for (int k=0;k<16;k++) m = fmaxf(m, red[tid][k]);
      rowmax[tid] = m;
    }
    __syncthreads();
    float m = rowmax[r];
    float sum = 0.f;
    for (int t = seg*64; t < seg*64+64; ++t) {
      float e = expf(sc[r][t]-m);
      sc[r][t] = e;               // masked entries become exact 0
      sum += e;
    }
    red[r][seg] = sum;
    __syncthreads();
    if (tid < QT) {
      float s2=0.f;
      for (int k=0;k<16;k++) s2 += red[tid][k];
      rowinv[tid] = 1.0f/s2;
    }
    __syncthreads();
  }

  // PV: o[r][c] = sum_t p * v ; masked p are 0 so loop to tile diagonal only
  int r = tid >> 4, c0 = tid & 15;
  float o0=0,o1=0,o2=0,o3=0;
  for (int t = 0; t < s0+QT; t += 4) {
    float4 p = *(const float4*)(&sc[r][t]);
    const float* vp = qkv + ((size_t)(b*S_ + t))*3072 + 2048 + h*DK_;
    o0 += p.x*vp[c0]        + p.y*vp[3072+c0]        + p.z*vp[2*3072+c0]        + p.w*vp[3*3072+c0];
    o1 += p.x*vp[c0+16]     + p.y*vp[3072+c0+16]     + p.z*vp[2*3072+c0+16]     + p.w*vp[3*3072+c0+16];
    o2 += p.x*vp[c0+32]     + p.y*vp[3072+c0+32]     + p.z*vp[2*3072+c0+32]     + p.w*vp[3*3072+c0+32];
    o3 += p.x*vp[c0+48]     + p.y*vp[3072+c0+48]     + p.z*vp[2*3072+c0+48]     + p.w*vp[3*3072+c0+48];
  }
  float inv = rowinv[r];
  float* op = out + ((size_t)(b*S_ + s0 + r))*D_ + h*DK_;
  op[c0] = o0*inv; op[c0+16] = o1*inv; op[c0+32] = o2*inv; op[c0+48] = o3*inv;
}

// ---------------- h = silu(g) * u ----------------
__global__ __launch_bounds__(256) void k_silumul(float* __restrict__ g,
    const float* __restrict__ u, int n) {
  int i = blockIdx.x*256 + threadIdx.x;
  if (i < n) {
    float v = g[i];
    float sg = v / (1.0f + expf(-v));
    g[i] = sg * u[i];
  }
}

extern "C" void kernel_launch(void* const* d_in, const int* in_sizes, int n_in,
                              void* d_out, int out_size, void* d_ws, size_t ws_size,
                              hipStream_t stream) {
  (void)in_sizes; (void)n_in; (void)out_size; (void)ws_size;
  const int*   ids  = (const int*)d_in[0];
  const float* emb  = (const float*)d_in[1];
  const float* wqkv = (const float*)d_in[2];
  const float* wo   = (const float*)d_in[3];
  const float* n1   = (const float*)d_in[4];
  const float* n2   = (const float*)d_in[5];
  const float* wg   = (const float*)d_in[6];
  const float* wu   = (const float*)d_in[7];
  const float* wd   = (const float*)d_in[8];
  const float* fnw  = (const float*)d_in[9];
  float* out = (float*)d_out;

  float* ws  = (float*)d_ws;
  float* x   = ws;                       // NT*D
  float* nx  = x   + (size_t)NT*D_;      // NT*D
  float* qkv = nx  + (size_t)NT*D_;      // NT*3D
  float* att = qkv + (size_t)NT*3*D_;    // NT*D
  float* g   = att + (size_t)NT*D_;      // NT*FF
  float* u   = g   + (size_t)NT*FF_;     // NT*FF

  dim3 blk(256);
  k_embed<<<(NT*D_+255)/256, blk, 0, stream>>>(ids, emb, x);
  for (int l = 0; l < L_; ++l) {
    k_rms<<<NT, blk, 0, stream>>>(x, n1 + (size_t)l*D_, nx);
    dim3 gqkv(3*D_/128, NT/128);
    k_gemm<false,false><<<gqkv, blk, 0, stream>>>(nx, wqkv + (size_t)l*D_*3*D_, nullptr, qkv, NT, 3*D_, D_);
    k_rope<<<(NT*2048+255)/256, blk, 0, stream>>>(qkv);
    dim3 gattn(S_/QT, H_, B_);
    k_attn<<<gattn, blk, 0, stream>>>(qkv, att);
    dim3 go(D_/128, NT/128);
    k_gemm<false,true><<<go, blk, 0, stream>>>(att, wo + (size_t)l*D_*D_, x, x, NT, D_, D_);
    k_rms<<<NT, blk, 0, stream>>>(x, n2 + (size_t)l*D_, nx);
    dim3 gff(FF_/128, NT/128);
    k_gemm<false,false><<<gff, blk, 0, stream>>>(nx, wg + (size_t)l*D_*FF_, nullptr, g, NT, FF_, D_);
    k_gemm<false,false><<<gff, blk, 0, stream>>>(nx, wu + (size_t)l*D_*FF_, nullptr, u, NT, FF_, D_);
    k_silumul<<<(NT*FF_+255)/256, blk, 0, stream>>>(g, u, NT*FF_);
    dim3 gd(D_/128, NT/128);
    k_gemm<false,true><<<gd, blk, 0, stream>>>(g, wd + (size_t)l*FF_*D_, x, x, NT, D_, FF_);
  }
  k_rms<<<NT, blk, 0, stream>>>(x, fnw, nx);
  dim3 glog(V_/128, NT/128);
  k_gemm<true,false><<<glog, blk, 0, stream>>>(nx, emb, nullptr, out, NT, V_, D_);
}

// Round 2
// 4025.594 us; speedup vs baseline: 3.3754x; 3.3754x over previous
//
#include <hip/hip_runtime.h>
#include <hip/hip_bf16.h>
#include <math.h>

#define B_ 2
#define S_ 1024
#define D_ 1024
#define H_ 16
#define DK_ 64
#define L_ 4
#define FF_ 4096
#define V_ 32000
#define NT (B_*S_)   // 2048 tokens
#define QT 16        // q rows per attention block

typedef __attribute__((ext_vector_type(8))) short short8v;
typedef __attribute__((ext_vector_type(4))) float floatx4;
typedef __hip_bfloat16 bf16;

__device__ inline float b2f(unsigned short u) {
  unsigned v = ((unsigned)u) << 16;
  float f; __builtin_memcpy(&f, &v, 4); return f;
}
__device__ inline unsigned short f2bu(float f) {
  bf16 h = __float2bfloat16(f);
  unsigned short u; __builtin_memcpy(&u, &h, 2); return u;
}

// ---------------- embed: x = emb[ids] * sqrt(D) (f32) ----------------
__global__ __launch_bounds__(256) void k_embed(const int* __restrict__ ids,
    const float* __restrict__ emb, float* __restrict__ x) {
  int i = blockIdx.x*256 + threadIdx.x;
  if (i >= NT*D_) return;
  int tok = i >> 10;
  int d = i & 1023;
  x[i] = emb[(size_t)ids[tok]*D_ + d] * 32.0f;
}

// ---------------- rmsnorm: o(bf16) = w * x / sqrt(mean(x^2)+1e-8) ----------
__global__ __launch_bounds__(256) void k_rms(const float* __restrict__ x,
    const float* __restrict__ w, bf16* __restrict__ o) {
  int row = blockIdx.x;
  const float* xr = x + (size_t)row*D_;
  float s = 0.f;
  for (int d = threadIdx.x; d < D_; d += 256) { float v = xr[d]; s += v*v; }
  for (int off = 32; off; off >>= 1) s += __shfl_down(s, off);
  __shared__ float red[4];
  __shared__ float inv_s;
  int wid = threadIdx.x >> 6;
  if ((threadIdx.x & 63) == 0) red[wid] = s;
  __syncthreads();
  if (threadIdx.x == 0) {
    float t = red[0]+red[1]+red[2]+red[3];
    inv_s = 1.0f / sqrtf(t * (1.0f/D_) + 1e-8f);
  }
  __syncthreads();
  float inv = inv_s;
  bf16* orow = o + (size_t)row*D_;
  for (int d = threadIdx.x; d < D_; d += 256) orow[d] = __float2bfloat16(w[d]*xr[d]*inv);
}

// ---------------- transpose+cast: src[K,N] f32 -> dst[N,K] bf16 ------------
__global__ __launch_bounds__(256) void k_transpose_cast(const float* __restrict__ src,
    bf16* __restrict__ dst, int K, int N) {
  __shared__ float t[32][33];
  int k0 = blockIdx.y*32, n0 = blockIdx.x*32;
  int tr = threadIdx.x >> 5, tc = threadIdx.x & 31;
  #pragma unroll
  for (int i=0;i<4;i++)
    t[tr + i*8][tc] = src[(size_t)(k0 + tr + i*8)*N + n0 + tc];
  __syncthreads();
  #pragma unroll
  for (int i=0;i<4;i++)
    dst[(size_t)(n0 + tr + i*8)*K + k0 + tc] = __float2bfloat16(t[tc][tr + i*8]);
}

// ---------------- cast f32 -> bf16, 4/thread ----------------
__global__ __launch_bounds__(256) void k_cast4(const float* __restrict__ s,
    bf16* __restrict__ d, int n4) {
  int i = blockIdx.x*256 + threadIdx.x;
  if (i >= n4) return;
  float4 v = ((const float4*)s)[i];
  ushort4 o;
  o.x = f2bu(v.x); o.y = f2bu(v.y); o.z = f2bu(v.z); o.w = f2bu(v.w);
  ((ushort4*)d)[i] = o;
}

// ---------------- MFMA GEMM: C[M,N] = A[M,K](bf16) @ Bt[N,K](bf16)^T -------
// 128x128 tile, BK=32, 256 threads (4 waves 2x2), each wave 64x64 out.
// RES: add f32 residual. OUTBF: write bf16 else f32.
template<bool RES, bool OUTBF>
__global__ __launch_bounds__(256) void k_mfma_gemm_bt(
    const bf16* __restrict__ A, const bf16* __restrict__ Bt,
    const float* __restrict__ res, void* __restrict__ Cout,
    int M, int N, int K) {
  __shared__ bf16 As[128*32];
  __shared__ bf16 Bs[128*32];
  const int tid  = threadIdx.x;
  const int lane = tid & 63;
  const int wave = tid >> 6;
  const int wm = (wave >> 1) * 64;
  const int wn = (wave & 1) * 64;
  const int bm = blockIdx.y * 128;
  const int bn = blockIdx.x * 128;

  floatx4 acc[4][4] = {};

  for (int k0 = 0; k0 < K; k0 += 32) {
    #pragma unroll
    for (int c = 0; c < 2; ++c) {
      int e = (c*256 + tid) * 8;          // element index in 128x32 tile
      int row = e >> 5, col = e & 31;
      const bf16* ga = A  + (size_t)(bm + row)*K + k0 + col;
      const bf16* gb = Bt + (size_t)(bn + row)*K + k0 + col;
      int ldsoff = (c*256 + wave*64) * 8; // wave-uniform, lane scatters +lane*16B
      __builtin_amdgcn_global_load_lds(
        (const __attribute__((address_space(1))) void*)ga,
        (__attribute__((address_space(3))) void*)(As + ldsoff), 16, 0, 0);
      __builtin_amdgcn_global_load_lds(
        (const __attribute__((address_space(1))) void*)gb,
        (__attribute__((address_space(3))) void*)(Bs + ldsoff), 16, 0, 0);
    }
    __syncthreads();
    const int r = lane & 15, kc = lane >> 4;
    short8v a[4], b[4];
    #pragma unroll
    for (int i = 0; i < 4; ++i) {
      a[i] = *(const short8v*)(As + (size_t)(wm + i*16 + r)*32 + kc*8);
      b[i] = *(const short8v*)(Bs + (size_t)(wn + i*16 + r)*32 + kc*8);
    }
    #pragma unroll
    for (int i = 0; i < 4; ++i)
      #pragma unroll
      for (int j = 0; j < 4; ++j)
        acc[i][j] = __builtin_amdgcn_mfma_f32_16x16x32_bf16(a[i], b[j], acc[i][j], 0, 0, 0);
    __syncthreads();
  }

  const int cn = lane & 15, rq = lane >> 4;
  #pragma unroll
  for (int i=0;i<4;i++) {
    #pragma unroll
    for (int j=0;j<4;j++) {
      #pragma unroll
      for (int rr=0; rr<4; ++rr) {
        int grow = bm + wm + i*16 + rq*4 + rr;
        int gcol = bn + wn + j*16 + cn;
        float v = acc[i][j][rr];
        if (RES) v += res[(size_t)grow*N + gcol];
        if (OUTBF) ((bf16*)Cout)[(size_t)grow*N + gcol] = __float2bfloat16(v);
        else       ((float*)Cout)[(size_t)grow*N + gcol] = v;
      }
    }
  }
}

// ---------------- RoPE factor multiply on bf16 qkv (q,k cols only) ---------
__global__ __launch_bounds__(256) void k_rope_bf(bf16* __restrict__ qkv) {
  int i = blockIdx.x*256 + threadIdx.x;
  if (i >= NT*2048) return;
  int tok = i >> 11;
  int c = i & 2047;              // cols [0,1024)=q, [1024,2048)=k
  int j = c & 31;
  int s = tok & (S_-1);
  float freq = expf((float)j * -0.28782313662425574f);  // -log(10000)/32
  float ang = (float)s * freq;
  size_t idx = (size_t)tok*3072 + c;
  unsigned short* p = (unsigned short*)qkv;
  p[idx] = f2bu(b2f(p[idx]) * (cosf(ang) + sinf(ang)));
}

// ---------------- attention (bf16 in/out, f32 compute) ----------------
__global__ __launch_bounds__(256) void k_attn_bf(const bf16* __restrict__ qkvb,
    bf16* __restrict__ out) {
  const unsigned short* qkv = (const unsigned short*)qkvb;
  const int qt = blockIdx.x;
  const int h  = blockIdx.y;
  const int b  = blockIdx.z;
  const int tid = threadIdx.x;
  __shared__ float q_s[QT][DK_];
  __shared__ float sc[QT][S_];        // 64 KB
  __shared__ float red[QT][17];
  __shared__ float rowmax[QT], rowinv[QT];

  const int s0 = qt*QT;
  for (int i = tid; i < QT*DK_; i += 256) {
    int r = i >> 6, c = i & 63;
    q_s[r][c] = b2f(qkv[((size_t)(b*S_ + s0 + r))*3072 + h*DK_ + c]);
  }
  __syncthreads();

  const int smax_tile = s0 + QT - 1;
  for (int t = tid; t < S_; t += 256) {
    if (t > smax_tile) {
      #pragma unroll
      for (int r=0;r<QT;r++) sc[r][t] = -1e9f;
      continue;
    }
    float acc[QT];
    #pragma unroll
    for (int r=0;r<QT;r++) acc[r]=0.f;
    const unsigned short* kp = qkv + ((size_t)(b*S_ + t))*3072 + 1024 + h*DK_;
    #pragma unroll
    for (int c=0;c<DK_;c+=4) {
      ushort4 kb = *(const ushort4*)(kp + c);
      float4 kv = make_float4(b2f(kb.x), b2f(kb.y), b2f(kb.z), b2f(kb.w));
      #pragma unroll
      for (int r=0;r<QT;r++) {
        float4 qv = *(const float4*)(&q_s[r][c]);
        acc[r] += qv.x*kv.x + qv.y*kv.y + qv.z*kv.z + qv.w*kv.w;
      }
    }
    #pragma unroll
    for (int r=0;r<QT;r++) sc[r][t] = (t <= s0+r) ? acc[r]*0.125f : -1e9f;
  }
  __syncthreads();

  {
    int r = tid & 15, seg = tid >> 4;
    float mx = -1e30f;
    for (int t = seg*64; t < seg*64+64; ++t) mx = fmaxf(mx, sc[r][t]);
    red[r][seg] = mx;
    __syncthreads();
    if (tid < QT) {
      float m = -1e30f;
      for (int k=0;k<16;k++) m = fmaxf(m, red[tid][k]);
      rowmax[tid] = m;
    }
    __syncthreads();
    float m = rowmax[r];
    float sum = 0.f;
    for (int t = seg*64; t < seg*64+64; ++t) {
      float e = expf(sc[r][t]-m);
      sc[r][t] = e;
      sum += e;
    }
    red[r][seg] = sum;
    __syncthreads();
    if (tid < QT) {
      float s2=0.f;
      for (int k=0;k<16;k++) s2 += red[tid][k];
      rowinv[tid] = 1.0f/s2;
    }
    __syncthreads();
  }

  int r = tid >> 4, c0 = tid & 15;
  float o0=0,o1=0,o2=0,o3=0;
  for (int t = 0; t < s0+QT; t += 4) {
    float4 p = *(const float4*)(&sc[r][t]);
    const unsigned short* vp = qkv + ((size_t)(b*S_ + t))*3072 + 2048 + h*DK_;
    o0 += p.x*b2f(vp[c0])      + p.y*b2f(vp[3072+c0])      + p.z*b2f(vp[2*3072+c0])      + p.w*b2f(vp[3*3072+c0]);
    o1 += p.x*b2f(vp[c0+16])   + p.y*b2f(vp[3072+c0+16])   + p.z*b2f(vp[2*3072+c0+16])   + p.w*b2f(vp[3*3072+c0+16]);
    o2 += p.x*b2f(vp[c0+32])   + p.y*b2f(vp[3072+c0+32])   + p.z*b2f(vp[2*3072+c0+32])   + p.w*b2f(vp[3*3072+c0+32]);
    o3 += p.x*b2f(vp[c0+48])   + p.y*b2f(vp[3072+c0+48])   + p.z*b2f(vp[2*3072+c0+48])   + p.w*b2f(vp[3*3072+c0+48]);
  }
  float inv = rowinv[r];
  bf16* op = out + ((size_t)(b*S_ + s0 + r))*D_ + h*DK_;
  op[c0]    = __float2bfloat16(o0*inv);
  op[c0+16] = __float2bfloat16(o1*inv);
  op[c0+32] = __float2bfloat16(o2*inv);
  op[c0+48] = __float2bfloat16(o3*inv);
}

// ---------------- h = silu(g) * u  (bf16 in, bf16 out in g) ----------------
__global__ __launch_bounds__(256) void k_silumul_bf(bf16* __restrict__ g,
    const bf16* __restrict__ u, int n) {
  int i = blockIdx.x*256 + threadIdx.x;
  if (i < n) {
    unsigned short* gp = (unsigned short*)g;
    float v = b2f(gp[i]);
    float sg = v / (1.0f + expf(-v));
    gp[i] = f2bu(sg * b2f(((const unsigned short*)u)[i]));
  }
}

extern "C" void kernel_launch(void* const* d_in, const int* in_sizes, int n_in,
                              void* d_out, int out_size, void* d_ws, size_t ws_size,
                              hipStream_t stream) {
  (void)in_sizes; (void)n_in; (void)out_size; (void)ws_size;
  const int*   ids  = (const int*)d_in[0];
  const float* emb  = (const float*)d_in[1];
  const float* wqkv = (const float*)d_in[2];
  const float* wo   = (const float*)d_in[3];
  const float* n1   = (const float*)d_in[4];
  const float* n2   = (const float*)d_in[5];
  const float* wg   = (const float*)d_in[6];
  const float* wu   = (const float*)d_in[7];
  const float* wd   = (const float*)d_in[8];
  const float* fnw  = (const float*)d_in[9];
  float* out = (float*)d_out;

  // ---- workspace layout (f32/bf16 mixed) ----
  char* ws = (char*)d_ws;
  float* x      = (float*)ws;                                   ws += (size_t)NT*D_*4;     // 8.39MB
  bf16*  nx_bf  = (bf16*)ws;                                    ws += (size_t)NT*D_*2;     // 4.19MB
  bf16*  att_bf = (bf16*)ws;                                    ws += (size_t)NT*D_*2;     // 4.19MB
  bf16*  shared = (bf16*)ws;                                    ws += (size_t)2*NT*FF_*2;  // 33.55MB
  bf16*  emb_bf = (bf16*)ws;                                    ws += (size_t)V_*D_*2;     // 65.54MB
  bf16*  qkv_bf = shared;                 // NT*3D, dead after attn
  bf16*  g_bf   = shared;                 // NT*FF
  bf16*  u_bf   = shared + (size_t)NT*FF_;

  // ---- bf16 transposed layer weights live in d_out (dead before logits) ----
  bf16* wsc = (bf16*)d_out;
  bf16* wqkv_t = wsc;                                  // 4 * 3072*1024
  bf16* wo_t   = wqkv_t + (size_t)L_*3*D_*D_;          // 4 * 1024*1024
  bf16* wg_t   = wo_t   + (size_t)L_*D_*D_;            // 4 * 4096*1024
  bf16* wu_t   = wg_t   + (size_t)L_*D_*FF_;
  bf16* wd_t   = wu_t   + (size_t)L_*D_*FF_;           // ends at 67.1M elems (134MB) < 262MB

  dim3 blk(256);

  // weight conversion (each call; deterministic)
  for (int l = 0; l < L_; ++l) {
    dim3 gq(3*D_/32, D_/32);
    k_transpose_cast<<<gq, blk, 0, stream>>>(wqkv + (size_t)l*D_*3*D_, wqkv_t + (size_t)l*3*D_*D_, D_, 3*D_);
    dim3 go(D_/32, D_/32);
    k_transpose_cast<<<go, blk, 0, stream>>>(wo + (size_t)l*D_*D_, wo_t + (size_t)l*D_*D_, D_, D_);
    dim3 gg(FF_/32, D_/32);
    k_transpose_cast<<<gg, blk, 0, stream>>>(wg + (size_t)l*D_*FF_, wg_t + (size_t)l*D_*FF_, D_, FF_);
    k_transpose_cast<<<gg, blk, 0, stream>>>(wu + (size_t)l*D_*FF_, wu_t + (size_t)l*D_*FF_, D_, FF_);
    dim3 gd(D_/32, FF_/32);
    k_transpose_cast<<<gd, blk, 0, stream>>>(wd + (size_t)l*FF_*D_, wd_t + (size_t)l*D_*FF_, FF_, D_);
  }
  k_cast4<<<(V_*D_/4 + 255)/256, blk, 0, stream>>>(emb, emb_bf, V_*D_/4);

  k_embed<<<(NT*D_+255)/256, blk, 0, stream>>>(ids, emb, x);

  for (int l = 0; l < L_; ++l) {
    k_rms<<<NT, blk, 0, stream>>>(x, n1 + (size_t)l*D_, nx_bf);
    dim3 gqkv(3*D_/128, NT/128);
    k_mfma_gemm_bt<false,true><<<gqkv, blk, 0, stream>>>(nx_bf, wqkv_t + (size_t)l*3*D_*D_, nullptr, qkv_bf, NT, 3*D_, D_);
    k_rope_bf<<<(NT*2048+255)/256, blk, 0, stream>>>(qkv_bf);
    dim3 gattn(S_/QT, H_, B_);
    k_attn_bf<<<gattn, blk, 0, stream>>>(qkv_bf, att_bf);
    dim3 go(D_/128, NT/128);
    k_mfma_gemm_bt<true,false><<<go, blk, 0, stream>>>(att_bf, wo_t + (size_t)l*D_*D_, x, x, NT, D_, D_);
    k_rms<<<NT, blk, 0, stream>>>(x, n2 + (size_t)l*D_, nx_bf);
    dim3 gff(FF_/128, NT/128);
    k_mfma_gemm_bt<false,true><<<gff, blk, 0, stream>>>(nx_bf, wg_t + (size_t)l*D_*FF_, nullptr, g_bf, NT, FF_, D_);
    k_mfma_gemm_bt<false,true><<<gff, blk, 0, stream>>>(nx_bf, wu_t + (size_t)l*D_*FF_, nullptr, u_bf, NT, FF_, D_);
    k_silumul_bf<<<(NT*FF_+255)/256, blk, 0, stream>>>(g_bf, u_bf, NT*FF_);
    dim3 gd2(D_/128, NT/128);
    k_mfma_gemm_bt<true,false><<<gd2, blk, 0, stream>>>(g_bf, wd_t + (size_t)l*D_*FF_, x, x, NT, D_, FF_);
  }
  k_rms<<<NT, blk, 0, stream>>>(x, fnw, nx_bf);
  dim3 glog(V_/128, NT/128);
  k_mfma_gemm_bt<false,false><<<glog, blk, 0, stream>>>(nx_bf, emb_bf, nullptr, out, NT, V_, D_);
}

// Round 3
// 1575.566 us; speedup vs baseline: 8.6242x; 2.5550x over previous
//
#include <hip/hip_runtime.h>
#include <hip/hip_bf16.h>
#include <math.h>

#define B_ 2
#define S_ 1024
#define D_ 1024
#define H_ 16
#define DK_ 64
#define L_ 4
#define FF_ 4096
#define V_ 32000
#define NT (B_*S_)   // 2048 tokens

typedef __attribute__((ext_vector_type(8))) short short8v;
typedef __attribute__((ext_vector_type(4))) float floatx4;
typedef __hip_bfloat16 bf16;

__device__ inline float b2f(unsigned short u) {
  unsigned v = ((unsigned)u) << 16;
  float f; __builtin_memcpy(&f, &v, 4); return f;
}
__device__ inline unsigned short f2bu(float f) {
  bf16 h = __float2bfloat16(f);
  unsigned short u; __builtin_memcpy(&u, &h, 2); return u;
}

// ---------------- embed: x = emb[ids] * sqrt(D) (f32) ----------------
__global__ __launch_bounds__(256) void k_embed(const int* __restrict__ ids,
    const float* __restrict__ emb, float* __restrict__ x) {
  int i = blockIdx.x*256 + threadIdx.x;
  if (i >= NT*D_) return;
  int tok = i >> 10;
  int d = i & 1023;
  x[i] = emb[(size_t)ids[tok]*D_ + d] * 32.0f;
}

// ---------------- rmsnorm: o(bf16) = w * x / sqrt(mean(x^2)+1e-8) ----------
__global__ __launch_bounds__(256) void k_rms(const float* __restrict__ x,
    const float* __restrict__ w, bf16* __restrict__ o) {
  int row = blockIdx.x;
  const float* xr = x + (size_t)row*D_;
  float s = 0.f;
  for (int d = threadIdx.x; d < D_; d += 256) { float v = xr[d]; s += v*v; }
  for (int off = 32; off; off >>= 1) s += __shfl_down(s, off);
  __shared__ float red[4];
  __shared__ float inv_s;
  int wid = threadIdx.x >> 6;
  if ((threadIdx.x & 63) == 0) red[wid] = s;
  __syncthreads();
  if (threadIdx.x == 0) {
    float t = red[0]+red[1]+red[2]+red[3];
    inv_s = 1.0f / sqrtf(t * (1.0f/D_) + 1e-8f);
  }
  __syncthreads();
  float inv = inv_s;
  bf16* orow = o + (size_t)row*D_;
  for (int d = threadIdx.x; d < D_; d += 256) orow[d] = __float2bfloat16(w[d]*xr[d]*inv);
}

// ---------------- transpose+cast: src[K,N] f32 -> dst[N,K] bf16 ------------
__global__ __launch_bounds__(256) void k_transpose_cast(const float* __restrict__ src,
    bf16* __restrict__ dst, int K, int N) {
  __shared__ float t[32][33];
  int k0 = blockIdx.y*32, n0 = blockIdx.x*32;
  int tr = threadIdx.x >> 5, tc = threadIdx.x & 31;
  #pragma unroll
  for (int i=0;i<4;i++)
    t[tr + i*8][tc] = src[(size_t)(k0 + tr + i*8)*N + n0 + tc];
  __syncthreads();
  #pragma unroll
  for (int i=0;i<4;i++)
    dst[(size_t)(n0 + tr + i*8)*K + k0 + tc] = __float2bfloat16(t[tc][tr + i*8]);
}

// ---------------- cast f32 -> bf16, 4/thread ----------------
__global__ __launch_bounds__(256) void k_cast4(const float* __restrict__ s,
    bf16* __restrict__ d, int n4) {
  int i = blockIdx.x*256 + threadIdx.x;
  if (i >= n4) return;
  float4 v = ((const float4*)s)[i];
  ushort4 o;
  o.x = f2bu(v.x); o.y = f2bu(v.y); o.z = f2bu(v.z); o.w = f2bu(v.w);
  ((ushort4*)d)[i] = o;
}

// ---------------- MFMA GEMM: C[M,N] = A[M,K](bf16) @ Bt[N,K](bf16)^T -------
template<bool RES, bool OUTBF>
__global__ __launch_bounds__(256) void k_mfma_gemm_bt(
    const bf16* __restrict__ A, const bf16* __restrict__ Bt,
    const float* __restrict__ res, void* __restrict__ Cout,
    int M, int N, int K) {
  __shared__ bf16 As[128*32];
  __shared__ bf16 Bs[128*32];
  const int tid  = threadIdx.x;
  const int lane = tid & 63;
  const int wave = tid >> 6;
  const int wm = (wave >> 1) * 64;
  const int wn = (wave & 1) * 64;
  const int bm = blockIdx.y * 128;
  const int bn = blockIdx.x * 128;

  floatx4 acc[4][4] = {};

  for (int k0 = 0; k0 < K; k0 += 32) {
    #pragma unroll
    for (int c = 0; c < 2; ++c) {
      int e = (c*256 + tid) * 8;
      int row = e >> 5, col = e & 31;
      const bf16* ga = A  + (size_t)(bm + row)*K + k0 + col;
      const bf16* gb = Bt + (size_t)(bn + row)*K + k0 + col;
      int ldsoff = (c*256 + wave*64) * 8;
      __builtin_amdgcn_global_load_lds(
        (const __attribute__((address_space(1))) void*)ga,
        (__attribute__((address_space(3))) void*)(As + ldsoff), 16, 0, 0);
      __builtin_amdgcn_global_load_lds(
        (const __attribute__((address_space(1))) void*)gb,
        (__attribute__((address_space(3))) void*)(Bs + ldsoff), 16, 0, 0);
    }
    __syncthreads();
    const int r = lane & 15, kc = lane >> 4;
    short8v a[4], b[4];
    #pragma unroll
    for (int i = 0; i < 4; ++i) {
      a[i] = *(const short8v*)(As + (size_t)(wm + i*16 + r)*32 + kc*8);
      b[i] = *(const short8v*)(Bs + (size_t)(wn + i*16 + r)*32 + kc*8);
    }
    #pragma unroll
    for (int i = 0; i < 4; ++i)
      #pragma unroll
      for (int j = 0; j < 4; ++j)
        acc[i][j] = __builtin_amdgcn_mfma_f32_16x16x32_bf16(a[i], b[j], acc[i][j], 0, 0, 0);
    __syncthreads();
  }

  const int cn = lane & 15, rq = lane >> 4;
  #pragma unroll
  for (int i=0;i<4;i++) {
    #pragma unroll
    for (int j=0;j<4;j++) {
      #pragma unroll
      for (int rr=0; rr<4; ++rr) {
        int grow = bm + wm + i*16 + rq*4 + rr;
        int gcol = bn + wn + j*16 + cn;
        float v = acc[i][j][rr];
        if (RES) v += res[(size_t)grow*N + gcol];
        if (OUTBF) ((bf16*)Cout)[(size_t)grow*N + gcol] = __float2bfloat16(v);
        else       ((float*)Cout)[(size_t)grow*N + gcol] = v;
      }
    }
  }
}

// ---------------- RoPE factor multiply on bf16 qkv (q,k cols only) ---------
__global__ __launch_bounds__(256) void k_rope_bf(bf16* __restrict__ qkv) {
  int i = blockIdx.x*256 + threadIdx.x;
  if (i >= NT*2048) return;
  int tok = i >> 11;
  int c = i & 2047;
  int j = c & 31;
  int s = tok & (S_-1);
  float freq = expf((float)j * -0.28782313662425574f);  // -log(10000)/32
  float ang = (float)s * freq;
  size_t idx = (size_t)tok*3072 + c;
  unsigned short* p = (unsigned short*)qkv;
  p[idx] = f2bu(b2f(p[idx]) * (cosf(ang) + sinf(ang)));
}

// ---------------- flash attention: MFMA, online softmax --------------------
// Grid (16 qtiles, H, B), 256 thr = 4 waves. Wave owns 16 q rows; KV tile 64.
// Swapped QK^T (S^T = K @ Q^T) so row-softmax is local+2 shuffles.
// K: global_load_lds with pre-swizzled source (slot = d16 ^ (t&7)).
// V: register-transposed to Vt[d][t], slot = (t>>3)^(d&7)^((d>>3)&7).
// P^T -> bf16 -> per-wave LDS (slot = c16 ^ (q&7)) -> A-frag for PV.
__global__ __launch_bounds__(256) void k_fattn(const bf16* __restrict__ qkvb,
    bf16* __restrict__ outb) {
  const unsigned short* qkv = (const unsigned short*)qkvb;
  const int qt = 15 - blockIdx.x;        // big tiles dispatch first
  const int h = blockIdx.y, b = blockIdx.z;
  const int tid = threadIdx.x, lane = tid & 63, w = tid >> 6;
  const int g = lane >> 4, qn = lane & 15;

  __shared__ unsigned short Ks[64*64];   // 8 KB, swizzled [t][slot]
  __shared__ unsigned short Vt[64*64];   // 8 KB, swizzled [d][slot]
  __shared__ unsigned short Ps[4*16*64]; // 8 KB, per-wave [q][slot]

  const int q0 = qt * 64;
  const int qw0 = q0 + w*16;

  // Q fragments (B-operand layout): lane holds Q[qw0+qn][g*8+j (+32*ks)]
  short8v qf[2];
  {
    const unsigned short* qp = qkv + ((size_t)(b*S_ + qw0 + qn))*3072 + h*DK_ + g*8;
    qf[0] = *(const short8v*)qp;
    qf[1] = *(const short8v*)(qp + 32);
  }

  floatx4 o_acc[4] = {};
  float m_run = -1e30f, l_run = 0.f;

  const int ntile = qt + 1;
  for (int it = 0; it < ntile; ++it) {
    const int t0 = it*64;

    // ---- stage K via global_load_lds, swizzled global source ----
    {
      const int trow = w*8 + (lane>>3);          // 0..31 within c-half
      const int d16 = (lane&7) ^ (trow&7);
      #pragma unroll
      for (int c = 0; c < 2; ++c) {
        const unsigned short* gk = qkv + ((size_t)(b*S_ + t0 + c*32 + trow))*3072
                                   + 1024 + h*DK_ + d16*8;
        __builtin_amdgcn_global_load_lds(
          (const __attribute__((address_space(1))) void*)gk,
          (__attribute__((address_space(3))) void*)(Ks + c*2048 + w*512), 16, 0, 0);
      }
    }
    // ---- stage V^T via register transpose ----
    #pragma unroll
    for (int c = 0; c < 2; ++c) {
      int idx = c*256 + tid;
      int t = idx >> 3;
      int d0 = (idx & 7)*8;
      short8v vv = *(const short8v*)(qkv + ((size_t)(b*S_ + t0 + t))*3072 + 2048 + h*DK_ + d0);
      #pragma unroll
      for (int jj = 0; jj < 8; ++jj) {
        int d = d0 + jj;
        int slot = ((t>>3) ^ (d&7) ^ ((d>>3)&7)) & 7;
        Vt[d*64 + slot*8 + (t&7)] = (unsigned short)vv[jj];
      }
    }
    __syncthreads();

    // ---- S^T = K @ Q^T ----
    floatx4 st[4];
    #pragma unroll
    for (int f = 0; f < 4; ++f) {
      st[f] = (floatx4){0.f,0.f,0.f,0.f};
      int t = f*16 + qn;
      #pragma unroll
      for (int ks = 0; ks < 2; ++ks) {
        int slot = ((ks*4 + g) ^ (t&7)) & 7;
        short8v kf = *(const short8v*)(Ks + t*64 + slot*8);
        st[f] = __builtin_amdgcn_mfma_f32_16x16x32_bf16(kf, qf[ks], st[f], 0,0,0);
      }
    }

    // ---- scale + causal mask + online softmax ----
    const bool diag = (it == qt);
    float sc[4][4];
    #pragma unroll
    for (int f = 0; f < 4; ++f)
      #pragma unroll
      for (int r = 0; r < 4; ++r) {
        float v = st[f][r]*0.125f;
        if (diag) {
          int tl = f*16 + g*4 + r;
          if (tl > w*16 + qn) v = -1e30f;
        }
        sc[f][r] = v;
      }
    float mx = -1e30f;
    #pragma unroll
    for (int f = 0; f < 4; ++f)
      #pragma unroll
      for (int r = 0; r < 4; ++r) mx = fmaxf(mx, sc[f][r]);
    mx = fmaxf(mx, __shfl_xor(mx, 16));
    mx = fmaxf(mx, __shfl_xor(mx, 32));
    float m_new = fmaxf(m_run, mx);
    float corr = __expf(m_run - m_new);
    m_run = m_new;
    float ls = 0.f;
    #pragma unroll
    for (int f = 0; f < 4; ++f)
      #pragma unroll
      for (int r = 0; r < 4; ++r) {
        float p = __expf(sc[f][r] - m_new);
        sc[f][r] = p;
        ls += p;
      }
    ls += __shfl_xor(ls, 16);
    ls += __shfl_xor(ls, 32);
    l_run = l_run*corr + ls;

    // ---- P^T -> bf16 -> per-wave LDS as P[q][t] ----
    unsigned short* Pw = Ps + w*1024;
    #pragma unroll
    for (int f = 0; f < 4; ++f) {
      unsigned int lo = (unsigned int)f2bu(sc[f][0]) | ((unsigned int)f2bu(sc[f][1]) << 16);
      unsigned int hi = (unsigned int)f2bu(sc[f][2]) | ((unsigned int)f2bu(sc[f][3]) << 16);
      int c16 = f*2 + (g>>1);
      int slot = (c16 ^ (qn&7)) & 7;
      *(uint2*)((char*)Pw + qn*128 + slot*16 + (g&1)*8) = make_uint2(lo, hi);
    }

    // ---- rescale O by corr ----
    #pragma unroll
    for (int r = 0; r < 4; ++r) {
      float cr = __shfl(corr, g*4 + r);
      #pragma unroll
      for (int fd = 0; fd < 4; ++fd) o_acc[fd][r] *= cr;
    }

    // ---- PV: O += P @ V ----
    short8v pf[2];
    #pragma unroll
    for (int ks = 0; ks < 2; ++ks) {
      int slot = ((ks*4 + g) ^ (qn&7)) & 7;
      pf[ks] = *(const short8v*)(Pw + qn*64 + slot*8);
    }
    #pragma unroll
    for (int fd = 0; fd < 4; ++fd) {
      int d = fd*16 + qn;
      #pragma unroll
      for (int ks = 0; ks < 2; ++ks) {
        int slot = ((ks*4 + g) ^ (d&7) ^ ((d>>3)&7)) & 7;
        short8v vf = *(const short8v*)(Vt + d*64 + slot*8);
        o_acc[fd] = __builtin_amdgcn_mfma_f32_16x16x32_bf16(pf[ks], vf, o_acc[fd], 0,0,0);
      }
    }
    __syncthreads();
  }

  // ---- epilogue: O /= l, write bf16 ----
  float linv = 1.0f / l_run;
  #pragma unroll
  for (int r = 0; r < 4; ++r) {
    float li = __shfl(linv, g*4 + r);
    int row = qw0 + g*4 + r;
    bf16* op = outb + (size_t)(b*S_ + row)*D_ + h*DK_ + qn;
    #pragma unroll
    for (int fd = 0; fd < 4; ++fd)
      op[fd*16] = __float2bfloat16(o_acc[fd][r] * li);
  }
}

// ---------------- h = silu(g) * u  (bf16 in, bf16 out in g) ----------------
__global__ __launch_bounds__(256) void k_silumul_bf(bf16* __restrict__ g,
    const bf16* __restrict__ u, int n) {
  int i = blockIdx.x*256 + threadIdx.x;
  if (i < n) {
    unsigned short* gp = (unsigned short*)g;
    float v = b2f(gp[i]);
    float sg = v / (1.0f + expf(-v));
    gp[i] = f2bu(sg * b2f(((const unsigned short*)u)[i]));
  }
}

extern "C" void kernel_launch(void* const* d_in, const int* in_sizes, int n_in,
                              void* d_out, int out_size, void* d_ws, size_t ws_size,
                              hipStream_t stream) {
  (void)in_sizes; (void)n_in; (void)out_size; (void)ws_size;
  const int*   ids  = (const int*)d_in[0];
  const float* emb  = (const float*)d_in[1];
  const float* wqkv = (const float*)d_in[2];
  const float* wo   = (const float*)d_in[3];
  const float* n1   = (const float*)d_in[4];
  const float* n2   = (const float*)d_in[5];
  const float* wg   = (const float*)d_in[6];
  const float* wu   = (const float*)d_in[7];
  const float* wd   = (const float*)d_in[8];
  const float* fnw  = (const float*)d_in[9];
  float* out = (float*)d_out;

  char* ws = (char*)d_ws;
  float* x      = (float*)ws;                                   ws += (size_t)NT*D_*4;
  bf16*  nx_bf  = (bf16*)ws;                                    ws += (size_t)NT*D_*2;
  bf16*  att_bf = (bf16*)ws;                                    ws += (size_t)NT*D_*2;
  bf16*  shared = (bf16*)ws;                                    ws += (size_t)2*NT*FF_*2;
  bf16*  emb_bf = (bf16*)ws;                                    ws += (size_t)V_*D_*2;
  bf16*  qkv_bf = shared;
  bf16*  g_bf   = shared;
  bf16*  u_bf   = shared + (size_t)NT*FF_;

  bf16* wsc = (bf16*)d_out;
  bf16* wqkv_t = wsc;
  bf16* wo_t   = wqkv_t + (size_t)L_*3*D_*D_;
  bf16* wg_t   = wo_t   + (size_t)L_*D_*D_;
  bf16* wu_t   = wg_t   + (size_t)L_*D_*FF_;
  bf16* wd_t   = wu_t   + (size_t)L_*D_*FF_;

  dim3 blk(256);

  for (int l = 0; l < L_; ++l) {
    dim3 gq(3*D_/32, D_/32);
    k_transpose_cast<<<gq, blk, 0, stream>>>(wqkv + (size_t)l*D_*3*D_, wqkv_t + (size_t)l*3*D_*D_, D_, 3*D_);
    dim3 go(D_/32, D_/32);
    k_transpose_cast<<<go, blk, 0, stream>>>(wo + (size_t)l*D_*D_, wo_t + (size_t)l*D_*D_, D_, D_);
    dim3 gg(FF_/32, D_/32);
    k_transpose_cast<<<gg, blk, 0, stream>>>(wg + (size_t)l*D_*FF_, wg_t + (size_t)l*D_*FF_, D_, FF_);
    k_transpose_cast<<<gg, blk, 0, stream>>>(wu + (size_t)l*D_*FF_, wu_t + (size_t)l*D_*FF_, D_, FF_);
    dim3 gd(D_/32, FF_/32);
    k_transpose_cast<<<gd, blk, 0, stream>>>(wd + (size_t)l*FF_*D_, wd_t + (size_t)l*D_*FF_, FF_, D_);
  }
  k_cast4<<<(V_*D_/4 + 255)/256, blk, 0, stream>>>(emb, emb_bf, V_*D_/4);

  k_embed<<<(NT*D_+255)/256, blk, 0, stream>>>(ids, emb, x);

  for (int l = 0; l < L_; ++l) {
    k_rms<<<NT, blk, 0, stream>>>(x, n1 + (size_t)l*D_, nx_bf);
    dim3 gqkv(3*D_/128, NT/128);
    k_mfma_gemm_bt<false,true><<<gqkv, blk, 0, stream>>>(nx_bf, wqkv_t + (size_t)l*3*D_*D_, nullptr, qkv_bf, NT, 3*D_, D_);
    k_rope_bf<<<(NT*2048+255)/256, blk, 0, stream>>>(qkv_bf);
    dim3 gattn(16, H_, B_);
    k_fattn<<<gattn, blk, 0, stream>>>(qkv_bf, att_bf);
    dim3 go(D_/128, NT/128);
    k_mfma_gemm_bt<true,false><<<go, blk, 0, stream>>>(att_bf, wo_t + (size_t)l*D_*D_, x, x, NT, D_, D_);
    k_rms<<<NT, blk, 0, stream>>>(x, n2 + (size_t)l*D_, nx_bf);
    dim3 gff(FF_/128, NT/128);
    k_mfma_gemm_bt<false,true><<<gff, blk, 0, stream>>>(nx_bf, wg_t + (size_t)l*D_*FF_, nullptr, g_bf, NT, FF_, D_);
    k_mfma_gemm_bt<false,true><<<gff, blk, 0, stream>>>(nx_bf, wu_t + (size_t)l*D_*FF_, nullptr, u_bf, NT, FF_, D_);
    k_silumul_bf<<<(NT*FF_+255)/256, blk, 0, stream>>>(g_bf, u_bf, NT*FF_);
    dim3 gd2(D_/128, NT/128);
    k_mfma_gemm_bt<true,false><<<gd2, blk, 0, stream>>>(g_bf, wd_t + (size_t)l*D_*FF_, x, x, NT, D_, FF_);
  }
  k_rms<<<NT, blk, 0, stream>>>(x, fnw, nx_bf);
  dim3 glog(V_/128, NT/128);
  k_mfma_gemm_bt<false,false><<<glog, blk, 0, stream>>>(nx_bf, emb_bf, nullptr, out, NT, V_, D_);
}